// Round 10
// baseline (193.647 us; speedup 1.0000x reference)
//
#include <hip/hip_runtime.h>
#include <stdint.h>

static constexpr int B_ = 512, N_ = 32, D_ = 256, K_ = 8;
static constexpr int E1 = 40, E2 = 6;          // ee MLP dims 256->40->6->1
static constexpr int N1 = 81, N2 = 25, N3 = 8; // en MLP dims 256->81->25->8
static constexpr int XBP = 264;                // xs_h row stride (f16), 528 B, 16B-aligned
static constexpr int H1P = 72;                 // h1t row stride (f16), 144 B
static constexpr int HEP = 88;                 // h1e row stride (f16)
static constexpr int EWT = 264;                // ew1T row stride (f16), 528 B
static constexpr int TKP = 44;                 // en tile k-stride (f16), 88 B (8B-aligned b64)
static constexpr float LN2f  = 0.69314718055994530942f;
static constexpr float L2Ef  = 1.44269504088896340736f;

typedef float    f32x4 __attribute__((ext_vector_type(4)));
typedef _Float16 f16x8 __attribute__((ext_vector_type(8)));
typedef _Float16 f16x4 __attribute__((ext_vector_type(4)));

// ssp(x) = log(0.5 e^x + 0.5) = ln2 * log2(0.5*2^(x*log2e) + 0.5); 5 VALU ops
__device__ __forceinline__ float sspf(float x) {
    float t = __builtin_amdgcn_exp2f(x * L2Ef);
    return LN2f * __builtin_amdgcn_logf(fmaf(t, 0.5f, 0.5f));
}

// single fused kernel; grid = B_ (one block per batch), 512 threads (8 waves)
__global__ __launch_bounds__(512, 4) void k_fused(
    const float* __restrict__ rs, const float* __restrict__ xs,
    const float* __restrict__ coords,
    const float* __restrict__ ew1, const float* __restrict__ eb1,
    const float* __restrict__ ew2, const float* __restrict__ eb2,
    const float* __restrict__ ew3, const float* __restrict__ eb3,
    const float* __restrict__ nw1, const float* __restrict__ nb1,
    const float* __restrict__ nw2, const float* __restrict__ nb2,
    const float* __restrict__ nw3, const float* __restrict__ nb3,
    float* __restrict__ out)
{
    __shared__ alignas(16) _Float16 xs_h[N_ * XBP];    // 16896 B
    __shared__ alignas(16) _Float16 wbuf[E1 * EWT];    // 21120 B: ew1T, then 2 en tiles (2*8448)
    __shared__ alignas(16) char uni[8 * 16 * H1P * 2]; // 18432 B: h1e+h2e, then h1t x8 waves
    __shared__ float nw2_s[N1 * N2];                   // 8100 B
    __shared__ float nw3_s[N2 * N3];
    __shared__ float rs_s[N_ * 3];
    __shared__ float nb2_s[N2];
    __shared__ float nb3_s[N3];
    __shared__ float co_s[K_ * 3];
    __shared__ float bfn_s[N_ * 3];
    __shared__ float cut_s[N_];
    __shared__ float bfe_s[N_ * 3];

    _Float16* h1e = (_Float16*)uni;                    // [32][HEP] f16 = 5632 B
    float*    h2e = (float*)(uni + N_ * HEP * 2);      // [32][26] f32 = 3328 B

    const int b = blockIdx.x, t = threadIdx.x;
    const int wv = t >> 6, l = t & 63, quad = l >> 4, c = l & 15;

    // ---- scalars + ee W2 frags from global (tiny, heavily L1-shared) ----
    f16x8 b2f[2];
    #pragma unroll
    for (int Kt = 0; Kt < 2; ++Kt) {
        union { uint32_t d[4]; f16x8 v; } f;
        #pragma unroll
        for (int d2 = 0; d2 < 4; ++d2) {
            int k0 = Kt * 32 + quad * 8 + 2 * d2;
            union { _Float16 h[2]; uint32_t u; } pk;
            pk.h[0] = (_Float16)((k0 < E1 && c < E2) ? ew2[k0 * E2 + c] : 0.f);
            pk.h[1] = (_Float16)((k0 + 1 < E1 && c < E2) ? ew2[(k0 + 1) * E2 + c] : 0.f);
            f.d[d2] = pk.u;
        }
        b2f[Kt] = f.v;
    }
    float eb1v[3];
    #pragma unroll
    for (int Nt = 0; Nt < 3; ++Nt) { int n = Nt * 16 + c; eb1v[Nt] = (n < E1) ? eb1[n] : 0.f; }
    const float eb2v = (c < E2) ? eb2[c] : 0.f;
    const float w3v  = (c < E2) ? ew3[c] : 0.f;
    const float eb3v = eb3[0];
    float nb1v[2];   // en layer-1 bias for products p = wv + 8e
    #pragma unroll
    for (int e = 0; e < 2; ++e) {
        int p = wv + 8 * e, n = (p >> 1) * 16 + c;
        nb1v[e] = (p < 12 && n < N1) ? nb1[n] : 0.f;
    }

    // ---- stage xs[b] fp32 -> fp16 LDS ----
    {
        const float4* src = (const float4*)(xs + (size_t)b * N_ * D_);
        #pragma unroll
        for (int u = 0; u < 4; ++u) {
            int q = t + 512 * u;              // 2048 float4
            float4 v = src[q];
            int row = q >> 6, col4 = q & 63;
            union { _Float16 h[4]; uint64_t u64; } pk;
            pk.h[0] = (_Float16)v.x; pk.h[1] = (_Float16)v.y;
            pk.h[2] = (_Float16)v.z; pk.h[3] = (_Float16)v.w;
            *(uint64_t*)&xs_h[row * XBP + col4 * 4] = pk.u64;
        }
    }
    // ---- stage ew1 [256][40] -> ew1T [40 n][264 k] f16 (transposed) ----
    {
        const float4* src = (const float4*)ew1;   // 2560 float4
        #pragma unroll
        for (int u = 0; u < 5; ++u) {
            int q = t + 512 * u;
            float4 v = src[q];
            int k = q / 10, n0 = (q - 10 * k) * 4;
            wbuf[(n0 + 0) * EWT + k] = (_Float16)v.x;
            wbuf[(n0 + 1) * EWT + k] = (_Float16)v.y;
            wbuf[(n0 + 2) * EWT + k] = (_Float16)v.z;
            wbuf[(n0 + 3) * EWT + k] = (_Float16)v.w;
        }
    }
    if (t < N_ * 3) rs_s[t] = rs[b * N_ * 3 + t];
    for (int i2 = t; i2 < N1 * N2; i2 += 512) nw2_s[i2] = nw2[i2];
    if (t < N2 * N3) nw3_s[t] = nw3[t];
    if (t < N2) nb2_s[t] = nb2[t];
    if (t < N3) nb3_s[t] = nb3[t];
    if (t < K_ * 3) co_s[t] = coords[t];
    __syncthreads();   // B1: xs_h + ew1T + weights ready

    // ---- build ee W1 fragments from ew1T (24 ds_read_b128 per lane) ----
    f16x8 b1f[3][8];
    #pragma unroll
    for (int Nt = 0; Nt < 3; ++Nt) {
        int n = Nt * 16 + c;
        bool ok = (n < E1);
        int row = ok ? n : 0;
        #pragma unroll
        for (int Kt = 0; Kt < 8; ++Kt) {
            f16x8 v = *(const f16x8*)&wbuf[row * EWT + Kt * 32 + quad * 8];
            if (!ok) v = (f16x8)(_Float16)0.f;
            b1f[Nt][Kt] = v;
        }
    }

    // ---- prefetch en tile 0 into registers (coalesced: lanes n-major) ----
    float pf[6];
    #pragma unroll
    for (int u = 0; u < 6; ++u) {
        int idx = t + 512 * u;                // 3072 = 32 k x 96 n
        int k = idx / 96, n = idx - 96 * k;
        pf[u] = (n < N1) ? nw1[k * N1 + n] : 0.f;
    }
    __syncthreads();   // B2: ew1T reads done; wbuf reusable for en tiles

    // ---- en layer 1 via MFMA, double-buffered swizzled tiles + reg prefetch ----
    {
        f32x4 acc3[2];
        #pragma unroll
        for (int e = 0; e < 2; ++e) acc3[e] = (f32x4){0.f, 0.f, 0.f, 0.f};

        #pragma unroll 1
        for (int Kt = 0; Kt < 8; ++Kt) {
            // write prefetched tile Kt -> LDS (XOR-8 swizzle on k keyed by n>>4 bit0)
            _Float16* dst = wbuf + (Kt & 1) * (96 * TKP);
            #pragma unroll
            for (int u = 0; u < 6; ++u) {
                int idx = t + 512 * u;
                int k = idx / 96, n = idx - 96 * k;
                int ks = k ^ (((n >> 4) & 1) << 3);
                dst[n * TKP + ks] = (_Float16)pf[u];
            }
            // issue prefetch for tile Kt+1 (consumed next iteration)
            if (Kt < 7) {
                const float* wk = nw1 + ((Kt + 1) * 32) * N1;
                #pragma unroll
                for (int u = 0; u < 6; ++u) {
                    int idx = t + 512 * u;
                    int k = idx / 96, n = idx - 96 * k;
                    pf[u] = (n < N1) ? wk[k * N1 + n] : 0.f;
                }
            }
            __syncthreads();                  // publish tile Kt
            const _Float16* T = wbuf + (Kt & 1) * (96 * TKP);
            #pragma unroll
            for (int e = 0; e < 2; ++e) {
                int p = wv + 8 * e;
                if (p < 12) {
                    int Mt = p & 1, Nt = p >> 1;
                    f16x8 A = *(const f16x8*)&xs_h[(Mt * 16 + c) * XBP + Kt * 32 + quad * 8];
                    int rb = (Nt * 16 + c) * TKP;
                    int kb = (quad * 8) ^ ((Nt & 1) << 3);
                    f16x4 lo = *(const f16x4*)&T[rb + kb];
                    f16x4 hi = *(const f16x4*)&T[rb + kb + 4];
                    f16x8 Bf = __builtin_shufflevector(lo, hi, 0, 1, 2, 3, 4, 5, 6, 7);
                    acc3[e] = __builtin_amdgcn_mfma_f32_16x16x32_f16(A, Bf, acc3[e], 0, 0, 0);
                }
            }
        }
        __syncthreads();                      // all reads of last tile done
        // epilogue: bias + ssp -> h1e (f16)
        #pragma unroll
        for (int e = 0; e < 2; ++e) {
            int p = wv + 8 * e;
            if (p < 12) {
                int Mt = p & 1, Nt = p >> 1;
                int n = Nt * 16 + c;
                if (n < N1) {
                    #pragma unroll
                    for (int r2 = 0; r2 < 4; ++r2) {
                        int m = Mt * 16 + quad * 4 + r2;
                        h1e[m * HEP + n] = (_Float16)sspf(acc3[e][r2] + nb1v[e]);
                    }
                }
            }
        }
    }
    __syncthreads();   // B12: h1e complete

    // ---- en layer 2 (VALU): 32 rows x 16 lanes, 2 cols each ----
    {
        const int r = t >> 4, s = t & 15;
        const int n0 = 2 * s;
        if (n0 < N2) {
            float a0 = 0.f, a1 = 0.f;
            const int rb = r * HEP;
            for (int kk = 0; kk < N1; ++kk) {
                float hv = (float)h1e[rb + kk];
                const float* wrow = nw2_s + kk * N2 + n0;
                a0 = fmaf(hv, wrow[0], a0);
                if (n0 + 1 < N2) a1 = fmaf(hv, wrow[1], a1);
            }
            h2e[r * 26 + n0] = sspf(a0 + nb2_s[n0]);
            if (n0 + 1 < N2) h2e[r * 26 + n0 + 1] = sspf(a1 + nb2_s[n0 + 1]);
        }
    }
    __syncthreads();   // B13: h2e complete

    // ---- en layer 3 + bf_nuc + cutoff (threads 0..255: 32 rows x 8 nuclei) ----
    if (t < 256) {
        const int r = t >> 3, s = t & 7;
        float w = nb3_s[s];
        const int rb = r * 26;
        #pragma unroll
        for (int kk = 0; kk < N2; ++kk)
            w = fmaf(h2e[rb + kk], nw3_s[kk * N3 + s], w);

        float dx = rs_s[r * 3 + 0] - co_s[s * 3 + 0];
        float dy = rs_s[r * 3 + 1] - co_s[s * 3 + 1];
        float dz = rs_s[r * 3 + 2] - co_s[s * 3 + 2];
        float cx = w * dx, cy = w * dy, cz = w * dz;
        #pragma unroll
        for (int m2 = 1; m2 < 8; m2 <<= 1) {
            cx += __shfl_xor(cx, m2);
            cy += __shfl_xor(cy, m2);
            cz += __shfl_xor(cz, m2);
        }
        float rr  = sqrtf(dx * dx + dy * dy + dz * dz);
        float xsc = 2.f * rr;                 // r / L, L = 0.5
        float cf  = (xsc < 0.5f) ? xsc * xsc * (6.f - 8.f * xsc + 3.f * xsc * xsc) : 1.f;
        #pragma unroll
        for (int m2 = 1; m2 < 8; m2 <<= 1) cf *= __shfl_xor(cf, m2);
        if (s == 0) {
            bfn_s[r * 3 + 0] = cx;
            bfn_s[r * 3 + 1] = cy;
            bfn_s[r * 3 + 2] = cz;
            cut_s[r] = cf;
        }
    }
    __syncthreads();   // B14: en done; uni free for h1t

    // zero h1t cols 48..63 (A-operand pad for layer-2 MFMA must be finite)
    _Float16* myh1 = (_Float16*)(uni + wv * (16 * H1P * 2));
    *(uint64_t*)&myh1[c * H1P + 48 + quad * 4] = 0ull;

    // ---- ee main: 4 i per wave; h=0/1 -> j=0..15 / 16..31 ----
    #pragma unroll 1
    for (int q8 = 0; q8 < 4; ++q8) {
        const int i = wv + 8 * q8;
        f32x4 acc[2][3];
        #pragma unroll
        for (int h = 0; h < 2; ++h)
            #pragma unroll
            for (int Nt = 0; Nt < 3; ++Nt) acc[h][Nt] = (f32x4){0.f, 0.f, 0.f, 0.f};

        #pragma unroll
        for (int Kt = 0; Kt < 8; ++Kt) {
            const int koff = Kt * 32 + quad * 8;
            f16x8 iv  = *(const f16x8*)&xs_h[i * XBP + koff];
            f16x8 jv0 = *(const f16x8*)&xs_h[c * XBP + koff];
            f16x8 jv1 = *(const f16x8*)&xs_h[(16 + c) * XBP + koff];
            f16x8 A0 = iv * jv0;               // v_pk_mul_f16 x4
            f16x8 A1 = iv * jv1;
            #pragma unroll
            for (int Nt = 0; Nt < 3; ++Nt) {
                acc[0][Nt] = __builtin_amdgcn_mfma_f32_16x16x32_f16(A0, b1f[Nt][Kt], acc[0][Nt], 0, 0, 0);
                acc[1][Nt] = __builtin_amdgcn_mfma_f32_16x16x32_f16(A1, b1f[Nt][Kt], acc[1][Nt], 0, 0, 0);
            }
        }

        // epilogue: h1 -> LDS swap -> layer2 MFMA -> layer3 -> inline contraction
        const float rix = rs_s[i * 3 + 0], riy = rs_s[i * 3 + 1], riz = rs_s[i * 3 + 2];
        float cxi = 0.f, cyi = 0.f, czi = 0.f;
        #pragma unroll
        for (int h = 0; h < 2; ++h) {
            #pragma unroll
            for (int Nt = 0; Nt < 3; ++Nt) {
                #pragma unroll
                for (int r2 = 0; r2 < 4; ++r2) {
                    float hv = sspf(acc[h][Nt][r2] + eb1v[Nt]);
                    myh1[(quad * 4 + r2) * H1P + Nt * 16 + c] = (_Float16)hv;
                }
            }
            f32x4 acc2 = {0.f, 0.f, 0.f, 0.f};
            #pragma unroll
            for (int Kt2 = 0; Kt2 < 2; ++Kt2) {
                f16x8 a2 = *(const f16x8*)&myh1[c * H1P + Kt2 * 32 + quad * 8];
                acc2 = __builtin_amdgcn_mfma_f32_16x16x32_f16(a2, b2f[Kt2], acc2, 0, 0, 0);
            }
            float wp[4];
            #pragma unroll
            for (int r2 = 0; r2 < 4; ++r2) wp[r2] = sspf(acc2[r2] + eb2v) * w3v;
            #pragma unroll
            for (int m2 = 1; m2 < 16; m2 <<= 1) {   // allreduce over c -> all lanes
                #pragma unroll
                for (int r2 = 0; r2 < 4; ++r2) wp[r2] += __shfl_xor(wp[r2], m2);
            }
            // contraction: this wave owns the full w[i][j] row across (quad,r2,h)
            #pragma unroll
            for (int r2 = 0; r2 < 4; ++r2) {
                int j = quad * 4 + r2 + 16 * h;
                float wj = wp[r2] + eb3v;
                cxi = fmaf(wj, rix - rs_s[j * 3 + 0], cxi);
                cyi = fmaf(wj, riy - rs_s[j * 3 + 1], cyi);
                czi = fmaf(wj, riz - rs_s[j * 3 + 2], czi);
            }
        }
        // reduce over quads (xor 16, 32), then lane 0 publishes bf_elec[i]
        #pragma unroll
        for (int m2 = 16; m2 < 64; m2 <<= 1) {
            cxi += __shfl_xor(cxi, m2);
            cyi += __shfl_xor(cyi, m2);
            czi += __shfl_xor(czi, m2);
        }
        if (l == 0) {
            bfe_s[i * 3 + 0] = cxi;
            bfe_s[i * 3 + 1] = cyi;
            bfe_s[i * 3 + 2] = czi;
        }
    }
    __syncthreads();   // B15: bfe_s ready

    // ---- final combine + store (threads 0..95) ----
    if (t < N_ * 3) {
        int i = t / 3;
        out[(size_t)b * (N_ * 3) + t] =
            rs_s[t] + 1e-4f * cut_s[i] * (bfe_s[t] + bfn_s[t]);
    }
}

extern "C" void kernel_launch(void* const* d_in, const int* in_sizes, int n_in,
                              void* d_out, int out_size, void* d_ws, size_t ws_size,
                              hipStream_t stream)
{
    const float* rs     = (const float*)d_in[0];
    const float* xs     = (const float*)d_in[1];
    const float* coords = (const float*)d_in[2];
    const float* ew1    = (const float*)d_in[3];
    const float* eb1    = (const float*)d_in[4];
    const float* ew2    = (const float*)d_in[5];
    const float* eb2    = (const float*)d_in[6];
    const float* ew3    = (const float*)d_in[7];
    const float* eb3    = (const float*)d_in[8];
    const float* nw1    = (const float*)d_in[9];
    const float* nb1    = (const float*)d_in[10];
    const float* nw2    = (const float*)d_in[11];
    const float* nb2    = (const float*)d_in[12];
    const float* nw3    = (const float*)d_in[13];
    const float* nb3    = (const float*)d_in[14];

    k_fused<<<B_, 512, 0, stream>>>(rs, xs, coords, ew1, eb1, ew2, eb2, ew3, eb3,
                                    nw1, nb1, nw2, nb2, nw3, nb3, (float*)d_out);
}

// Round 11
// 146.576 us; speedup vs baseline: 1.3211x; 1.3211x over previous
//
#include <hip/hip_runtime.h>
#include <stdint.h>

static constexpr int B_ = 512, N_ = 32, D_ = 256, K_ = 8;
static constexpr int E1 = 40, E2 = 6;          // ee MLP dims 256->40->6->1
static constexpr int N1 = 81, N2 = 25, N3 = 8; // en MLP dims 256->81->25->8
static constexpr int XBP = 264;                // xs_h row stride (f16), 528 B, 16B-aligned
static constexpr int H1P = 72;                 // h1t row stride (f16), 144 B
static constexpr int HEP = 88;                 // h1e row stride (f16)
static constexpr int EWT = 264;                // ew1T row stride (f16), 528 B
static constexpr int TKP = 44;                 // en tile k-stride (f16), 88 B (8B-aligned b64)
static constexpr float LN2f  = 0.69314718055994530942f;
static constexpr float L2Ef  = 1.44269504088896340736f;

typedef float    f32x4 __attribute__((ext_vector_type(4)));
typedef _Float16 f16x8 __attribute__((ext_vector_type(8)));
typedef _Float16 f16x4 __attribute__((ext_vector_type(4)));

// ssp(x) = log(0.5 e^x + 0.5) = ln2 * log2(0.5*2^(x*log2e) + 0.5); 5 VALU ops
__device__ __forceinline__ float sspf(float x) {
    float t = __builtin_amdgcn_exp2f(x * L2Ef);
    return LN2f * __builtin_amdgcn_logf(fmaf(t, 0.5f, 0.5f));
}

// single fused kernel; grid = B_ (one block per batch), 512 threads (8 waves)
// NOTE: no occupancy arg in launch_bounds — pinning it forced VGPR<=64 and
// spilled the 96-VGPR b1f fragment file (R10: FETCH 274MB). Allocator floats
// to 128 VGPR naturally (R9), giving 2 blocks/CU with LDS ~70KB.
__global__ __launch_bounds__(512) void k_fused(
    const float* __restrict__ rs, const float* __restrict__ xs,
    const float* __restrict__ coords,
    const float* __restrict__ ew1, const float* __restrict__ eb1,
    const float* __restrict__ ew2, const float* __restrict__ eb2,
    const float* __restrict__ ew3, const float* __restrict__ eb3,
    const float* __restrict__ nw1, const float* __restrict__ nb1,
    const float* __restrict__ nw2, const float* __restrict__ nb2,
    const float* __restrict__ nw3, const float* __restrict__ nb3,
    float* __restrict__ out)
{
    __shared__ alignas(16) _Float16 xs_h[N_ * XBP];    // 16896 B
    __shared__ alignas(16) _Float16 wbuf[E1 * EWT];    // 21120 B: ew1T, then 2 en tiles (2*8448)
    __shared__ alignas(16) char uni[8 * 16 * H1P * 2]; // 18432 B: h1e+h2e, then h1t x8 waves
    __shared__ float nw2_s[N1 * N2];                   // 8100 B
    __shared__ float nw3_s[N2 * N3];
    __shared__ float rs_s[N_ * 3];
    __shared__ float nb2_s[N2];
    __shared__ float nb3_s[N3];
    __shared__ float co_s[K_ * 3];
    __shared__ float bfn_s[N_ * 3];
    __shared__ float cut_s[N_];
    __shared__ float bfe_s[N_ * 3];

    _Float16* h1e = (_Float16*)uni;                    // [32][HEP] f16 = 5632 B
    float*    h2e = (float*)(uni + N_ * HEP * 2);      // [32][26] f32 = 3328 B

    const int b = blockIdx.x, t = threadIdx.x;
    const int wv = t >> 6, l = t & 63, quad = l >> 4, c = l & 15;

    // ---- scalars + ee W2 frags from global (tiny, heavily L1-shared) ----
    f16x8 b2f[2];
    #pragma unroll
    for (int Kt = 0; Kt < 2; ++Kt) {
        union { uint32_t d[4]; f16x8 v; } f;
        #pragma unroll
        for (int d2 = 0; d2 < 4; ++d2) {
            int k0 = Kt * 32 + quad * 8 + 2 * d2;
            union { _Float16 h[2]; uint32_t u; } pk;
            pk.h[0] = (_Float16)((k0 < E1 && c < E2) ? ew2[k0 * E2 + c] : 0.f);
            pk.h[1] = (_Float16)((k0 + 1 < E1 && c < E2) ? ew2[(k0 + 1) * E2 + c] : 0.f);
            f.d[d2] = pk.u;
        }
        b2f[Kt] = f.v;
    }
    float eb1v[3];
    #pragma unroll
    for (int Nt = 0; Nt < 3; ++Nt) { int n = Nt * 16 + c; eb1v[Nt] = (n < E1) ? eb1[n] : 0.f; }
    const float eb2v = (c < E2) ? eb2[c] : 0.f;
    const float w3v  = (c < E2) ? ew3[c] : 0.f;
    const float eb3v = eb3[0];
    float nb1v[2];   // en layer-1 bias for products p = wv + 8e
    #pragma unroll
    for (int e = 0; e < 2; ++e) {
        int p = wv + 8 * e, n = (p >> 1) * 16 + c;
        nb1v[e] = (p < 12 && n < N1) ? nb1[n] : 0.f;
    }

    // ---- stage xs[b] fp32 -> fp16 LDS ----
    {
        const float4* src = (const float4*)(xs + (size_t)b * N_ * D_);
        #pragma unroll
        for (int u = 0; u < 4; ++u) {
            int q = t + 512 * u;              // 2048 float4
            float4 v = src[q];
            int row = q >> 6, col4 = q & 63;
            union { _Float16 h[4]; uint64_t u64; } pk;
            pk.h[0] = (_Float16)v.x; pk.h[1] = (_Float16)v.y;
            pk.h[2] = (_Float16)v.z; pk.h[3] = (_Float16)v.w;
            *(uint64_t*)&xs_h[row * XBP + col4 * 4] = pk.u64;
        }
    }
    // ---- stage ew1 [256][40] -> ew1T [40 n][264 k] f16 (transposed) ----
    {
        const float4* src = (const float4*)ew1;   // 2560 float4
        #pragma unroll
        for (int u = 0; u < 5; ++u) {
            int q = t + 512 * u;
            float4 v = src[q];
            int k = q / 10, n0 = (q - 10 * k) * 4;
            wbuf[(n0 + 0) * EWT + k] = (_Float16)v.x;
            wbuf[(n0 + 1) * EWT + k] = (_Float16)v.y;
            wbuf[(n0 + 2) * EWT + k] = (_Float16)v.z;
            wbuf[(n0 + 3) * EWT + k] = (_Float16)v.w;
        }
    }
    if (t < N_ * 3) rs_s[t] = rs[b * N_ * 3 + t];
    for (int i2 = t; i2 < N1 * N2; i2 += 512) nw2_s[i2] = nw2[i2];
    if (t < N2 * N3) nw3_s[t] = nw3[t];
    if (t < N2) nb2_s[t] = nb2[t];
    if (t < N3) nb3_s[t] = nb3[t];
    if (t < K_ * 3) co_s[t] = coords[t];
    __syncthreads();   // B1: xs_h + ew1T + weights ready

    // ---- build ee W1 fragments from ew1T (24 ds_read_b128 per lane) ----
    f16x8 b1f[3][8];
    #pragma unroll
    for (int Nt = 0; Nt < 3; ++Nt) {
        int n = Nt * 16 + c;
        bool ok = (n < E1);
        int row = ok ? n : 0;
        #pragma unroll
        for (int Kt = 0; Kt < 8; ++Kt) {
            f16x8 v = *(const f16x8*)&wbuf[row * EWT + Kt * 32 + quad * 8];
            if (!ok) v = (f16x8)(_Float16)0.f;
            b1f[Nt][Kt] = v;
        }
    }

    // ---- prefetch en tile 0 into registers (coalesced: lanes n-major) ----
    float pf[6];
    #pragma unroll
    for (int u = 0; u < 6; ++u) {
        int idx = t + 512 * u;                // 3072 = 32 k x 96 n
        int k = idx / 96, n = idx - 96 * k;
        pf[u] = (n < N1) ? nw1[k * N1 + n] : 0.f;
    }
    __syncthreads();   // B2: ew1T reads done; wbuf reusable for en tiles

    // ---- en layer 1 via MFMA, double-buffered swizzled tiles + reg prefetch ----
    {
        f32x4 acc3[2];
        #pragma unroll
        for (int e = 0; e < 2; ++e) acc3[e] = (f32x4){0.f, 0.f, 0.f, 0.f};

        #pragma unroll 1
        for (int Kt = 0; Kt < 8; ++Kt) {
            // write prefetched tile Kt -> LDS (XOR-8 swizzle on k keyed by n>>4 bit0)
            _Float16* dst = wbuf + (Kt & 1) * (96 * TKP);
            #pragma unroll
            for (int u = 0; u < 6; ++u) {
                int idx = t + 512 * u;
                int k = idx / 96, n = idx - 96 * k;
                int ks = k ^ (((n >> 4) & 1) << 3);
                dst[n * TKP + ks] = (_Float16)pf[u];
            }
            // issue prefetch for tile Kt+1 (consumed next iteration)
            if (Kt < 7) {
                const float* wk = nw1 + ((Kt + 1) * 32) * N1;
                #pragma unroll
                for (int u = 0; u < 6; ++u) {
                    int idx = t + 512 * u;
                    int k = idx / 96, n = idx - 96 * k;
                    pf[u] = (n < N1) ? wk[k * N1 + n] : 0.f;
                }
            }
            __syncthreads();                  // publish tile Kt
            const _Float16* T = wbuf + (Kt & 1) * (96 * TKP);
            #pragma unroll
            for (int e = 0; e < 2; ++e) {
                int p = wv + 8 * e;
                if (p < 12) {
                    int Mt = p & 1, Nt = p >> 1;
                    f16x8 A = *(const f16x8*)&xs_h[(Mt * 16 + c) * XBP + Kt * 32 + quad * 8];
                    int rb = (Nt * 16 + c) * TKP;
                    int kb = (quad * 8) ^ ((Nt & 1) << 3);
                    f16x4 lo = *(const f16x4*)&T[rb + kb];
                    f16x4 hi = *(const f16x4*)&T[rb + kb + 4];
                    f16x8 Bf = __builtin_shufflevector(lo, hi, 0, 1, 2, 3, 4, 5, 6, 7);
                    acc3[e] = __builtin_amdgcn_mfma_f32_16x16x32_f16(A, Bf, acc3[e], 0, 0, 0);
                }
            }
        }
        __syncthreads();                      // all reads of last tile done
        // epilogue: bias + ssp -> h1e (f16)
        #pragma unroll
        for (int e = 0; e < 2; ++e) {
            int p = wv + 8 * e;
            if (p < 12) {
                int Mt = p & 1, Nt = p >> 1;
                int n = Nt * 16 + c;
                if (n < N1) {
                    #pragma unroll
                    for (int r2 = 0; r2 < 4; ++r2) {
                        int m = Mt * 16 + quad * 4 + r2;
                        h1e[m * HEP + n] = (_Float16)sspf(acc3[e][r2] + nb1v[e]);
                    }
                }
            }
        }
    }
    __syncthreads();   // B12: h1e complete

    // ---- en layer 2 (VALU): 32 rows x 16 lanes, 2 cols each ----
    {
        const int r = t >> 4, s = t & 15;
        const int n0 = 2 * s;
        if (n0 < N2) {
            float a0 = 0.f, a1 = 0.f;
            const int rb = r * HEP;
            for (int kk = 0; kk < N1; ++kk) {
                float hv = (float)h1e[rb + kk];
                const float* wrow = nw2_s + kk * N2 + n0;
                a0 = fmaf(hv, wrow[0], a0);
                if (n0 + 1 < N2) a1 = fmaf(hv, wrow[1], a1);
            }
            h2e[r * 26 + n0] = sspf(a0 + nb2_s[n0]);
            if (n0 + 1 < N2) h2e[r * 26 + n0 + 1] = sspf(a1 + nb2_s[n0 + 1]);
        }
    }
    __syncthreads();   // B13: h2e complete

    // ---- en layer 3 + bf_nuc + cutoff (threads 0..255: 32 rows x 8 nuclei) ----
    if (t < 256) {
        const int r = t >> 3, s = t & 7;
        float w = nb3_s[s];
        const int rb = r * 26;
        #pragma unroll
        for (int kk = 0; kk < N2; ++kk)
            w = fmaf(h2e[rb + kk], nw3_s[kk * N3 + s], w);

        float dx = rs_s[r * 3 + 0] - co_s[s * 3 + 0];
        float dy = rs_s[r * 3 + 1] - co_s[s * 3 + 1];
        float dz = rs_s[r * 3 + 2] - co_s[s * 3 + 2];
        float cx = w * dx, cy = w * dy, cz = w * dz;
        #pragma unroll
        for (int m2 = 1; m2 < 8; m2 <<= 1) {
            cx += __shfl_xor(cx, m2);
            cy += __shfl_xor(cy, m2);
            cz += __shfl_xor(cz, m2);
        }
        float rr  = sqrtf(dx * dx + dy * dy + dz * dz);
        float xsc = 2.f * rr;                 // r / L, L = 0.5
        float cf  = (xsc < 0.5f) ? xsc * xsc * (6.f - 8.f * xsc + 3.f * xsc * xsc) : 1.f;
        #pragma unroll
        for (int m2 = 1; m2 < 8; m2 <<= 1) cf *= __shfl_xor(cf, m2);
        if (s == 0) {
            bfn_s[r * 3 + 0] = cx;
            bfn_s[r * 3 + 1] = cy;
            bfn_s[r * 3 + 2] = cz;
            cut_s[r] = cf;
        }
    }
    __syncthreads();   // B14: en done; uni free for h1t

    // zero h1t cols 48..63 (A-operand pad for layer-2 MFMA must be finite)
    _Float16* myh1 = (_Float16*)(uni + wv * (16 * H1P * 2));
    *(uint64_t*)&myh1[c * H1P + 48 + quad * 4] = 0ull;

    // ---- ee main: 4 i per wave; h=0/1 -> j=0..15 / 16..31 ----
    #pragma unroll 1
    for (int q8 = 0; q8 < 4; ++q8) {
        const int i = wv + 8 * q8;
        f32x4 acc[2][3];
        #pragma unroll
        for (int h = 0; h < 2; ++h)
            #pragma unroll
            for (int Nt = 0; Nt < 3; ++Nt) acc[h][Nt] = (f32x4){0.f, 0.f, 0.f, 0.f};

        #pragma unroll
        for (int Kt = 0; Kt < 8; ++Kt) {
            const int koff = Kt * 32 + quad * 8;
            f16x8 iv  = *(const f16x8*)&xs_h[i * XBP + koff];
            f16x8 jv0 = *(const f16x8*)&xs_h[c * XBP + koff];
            f16x8 jv1 = *(const f16x8*)&xs_h[(16 + c) * XBP + koff];
            f16x8 A0 = iv * jv0;               // v_pk_mul_f16 x4
            f16x8 A1 = iv * jv1;
            #pragma unroll
            for (int Nt = 0; Nt < 3; ++Nt) {
                acc[0][Nt] = __builtin_amdgcn_mfma_f32_16x16x32_f16(A0, b1f[Nt][Kt], acc[0][Nt], 0, 0, 0);
                acc[1][Nt] = __builtin_amdgcn_mfma_f32_16x16x32_f16(A1, b1f[Nt][Kt], acc[1][Nt], 0, 0, 0);
            }
        }

        // epilogue: h1 -> LDS swap -> layer2 MFMA -> layer3 -> inline contraction
        const float rix = rs_s[i * 3 + 0], riy = rs_s[i * 3 + 1], riz = rs_s[i * 3 + 2];
        float cxi = 0.f, cyi = 0.f, czi = 0.f;
        #pragma unroll
        for (int h = 0; h < 2; ++h) {
            #pragma unroll
            for (int Nt = 0; Nt < 3; ++Nt) {
                #pragma unroll
                for (int r2 = 0; r2 < 4; ++r2) {
                    float hv = sspf(acc[h][Nt][r2] + eb1v[Nt]);
                    myh1[(quad * 4 + r2) * H1P + Nt * 16 + c] = (_Float16)hv;
                }
            }
            f32x4 acc2 = {0.f, 0.f, 0.f, 0.f};
            #pragma unroll
            for (int Kt2 = 0; Kt2 < 2; ++Kt2) {
                f16x8 a2 = *(const f16x8*)&myh1[c * H1P + Kt2 * 32 + quad * 8];
                acc2 = __builtin_amdgcn_mfma_f32_16x16x32_f16(a2, b2f[Kt2], acc2, 0, 0, 0);
            }
            float wp[4];
            #pragma unroll
            for (int r2 = 0; r2 < 4; ++r2) wp[r2] = sspf(acc2[r2] + eb2v) * w3v;
            #pragma unroll
            for (int m2 = 1; m2 < 16; m2 <<= 1) {   // allreduce over c -> all lanes
                #pragma unroll
                for (int r2 = 0; r2 < 4; ++r2) wp[r2] += __shfl_xor(wp[r2], m2);
            }
            // contraction: this wave owns the full w[i][j] row across (quad,r2,h)
            #pragma unroll
            for (int r2 = 0; r2 < 4; ++r2) {
                int j = quad * 4 + r2 + 16 * h;
                float wj = wp[r2] + eb3v;
                cxi = fmaf(wj, rix - rs_s[j * 3 + 0], cxi);
                cyi = fmaf(wj, riy - rs_s[j * 3 + 1], cyi);
                czi = fmaf(wj, riz - rs_s[j * 3 + 2], czi);
            }
        }
        // reduce over quads (xor 16, 32), then lane 0 publishes bf_elec[i]
        #pragma unroll
        for (int m2 = 16; m2 < 64; m2 <<= 1) {
            cxi += __shfl_xor(cxi, m2);
            cyi += __shfl_xor(cyi, m2);
            czi += __shfl_xor(czi, m2);
        }
        if (l == 0) {
            bfe_s[i * 3 + 0] = cxi;
            bfe_s[i * 3 + 1] = cyi;
            bfe_s[i * 3 + 2] = czi;
        }
    }
    __syncthreads();   // B15: bfe_s ready

    // ---- final combine + store (threads 0..95) ----
    if (t < N_ * 3) {
        int i = t / 3;
        out[(size_t)b * (N_ * 3) + t] =
            rs_s[t] + 1e-4f * cut_s[i] * (bfe_s[t] + bfn_s[t]);
    }
}

extern "C" void kernel_launch(void* const* d_in, const int* in_sizes, int n_in,
                              void* d_out, int out_size, void* d_ws, size_t ws_size,
                              hipStream_t stream)
{
    const float* rs     = (const float*)d_in[0];
    const float* xs     = (const float*)d_in[1];
    const float* coords = (const float*)d_in[2];
    const float* ew1    = (const float*)d_in[3];
    const float* eb1    = (const float*)d_in[4];
    const float* ew2    = (const float*)d_in[5];
    const float* eb2    = (const float*)d_in[6];
    const float* ew3    = (const float*)d_in[7];
    const float* eb3    = (const float*)d_in[8];
    const float* nw1    = (const float*)d_in[9];
    const float* nb1    = (const float*)d_in[10];
    const float* nw2    = (const float*)d_in[11];
    const float* nb2    = (const float*)d_in[12];
    const float* nw3    = (const float*)d_in[13];
    const float* nb3    = (const float*)d_in[14];

    k_fused<<<B_, 512, 0, stream>>>(rs, xs, coords, ew1, eb1, ew2, eb2, ew3, eb3,
                                    nw1, nb1, nw2, nb2, nw3, nb3, (float*)d_out);
}

// Round 12
// 133.846 us; speedup vs baseline: 1.4468x; 1.0951x over previous
//
#include <hip/hip_runtime.h>
#include <stdint.h>

static constexpr int B_ = 512, N_ = 32, D_ = 256, K_ = 8;
static constexpr int E1 = 40, E2 = 6;          // ee MLP dims 256->40->6->1
static constexpr int N1 = 81, N2 = 25, N3 = 8; // en MLP dims 256->81->25->8
static constexpr int XBP = 264;                // xs_h row stride (f16), 528 B, 16B-aligned
static constexpr int H1P = 72;                 // h1t row stride (f16), 144 B
static constexpr int HEP = 96;                 // h1e row stride (f16), 192 B, 16B-aligned
static constexpr int EWT = 264;                // ew1T row stride (f16), 528 B
static constexpr int TKP = 48;                 // en tile k-stride (f16), 96 B, 16B-aligned
static constexpr int NWP = 104;                // nw2T row stride (f16), 208 B, 16B-aligned
static constexpr int TILE16 = 16 * TKP;       // per-wave en tile, f16 elems (1536 B)
static constexpr float LN2f  = 0.69314718055994530942f;
static constexpr float L2Ef  = 1.44269504088896340736f;

typedef float    f32x4 __attribute__((ext_vector_type(4)));
typedef _Float16 f16x8 __attribute__((ext_vector_type(8)));

// ssp(x) = log(0.5 e^x + 0.5) = ln2 * log2(0.5*2^(x*log2e) + 0.5); 5 VALU ops
__device__ __forceinline__ float sspf(float x) {
    float t = __builtin_amdgcn_exp2f(x * L2Ef);
    return LN2f * __builtin_amdgcn_logf(fmaf(t, 0.5f, 0.5f));
}

// single fused kernel; grid = B_ (one block per batch), 512 threads (8 waves)
// NOTE: no occupancy arg in launch_bounds (R10: pinning forced VGPR<=64 and
// spilled b1f; allocator floats to 128 = 2 blocks/CU).
__global__ __launch_bounds__(512) void k_fused(
    const float* __restrict__ rs, const float* __restrict__ xs,
    const float* __restrict__ coords,
    const float* __restrict__ ew1, const float* __restrict__ eb1,
    const float* __restrict__ ew2, const float* __restrict__ eb2,
    const float* __restrict__ ew3, const float* __restrict__ eb3,
    const float* __restrict__ nw1, const float* __restrict__ nb1,
    const float* __restrict__ nw2, const float* __restrict__ nb2,
    const float* __restrict__ nw3, const float* __restrict__ nb3,
    float* __restrict__ out)
{
    __shared__ alignas(16) _Float16 xs_h[N_ * XBP];    // 16896 B
    __shared__ alignas(16) _Float16 wbuf[E1 * EWT];    // 21120 B: ew1T (until b1f built)
    // uni (18688 B), time-multiplexed:
    //   en phase: [0,9216) 6 per-wave nw1 tiles -> then nw2T (6656 B)
    //             [9216,15360) h1e f16 [32][96]; [15360,18688) h2e f32 [32][26]
    //   ee phase: h1t[8 waves][16][H1P] f16 (18432 B)
    __shared__ alignas(16) char uni[18688];
    __shared__ float nw3_s[N2 * N3];
    __shared__ float rs_s[N_ * 3];
    __shared__ float nb2_s[N2];
    __shared__ float nb3_s[N3];
    __shared__ float co_s[K_ * 3];
    __shared__ float bfn_s[N_ * 3];
    __shared__ float cut_s[N_];
    __shared__ float bfe_s[N_ * 3];

    _Float16* h1e  = (_Float16*)(uni + 9216);          // [32][HEP]
    float*    h2e  = (float*)(uni + 15360);            // [32][26]
    _Float16* nw2T = (_Float16*)uni;                   // [32][NWP] (en L2 phase)

    const int b = blockIdx.x, t = threadIdx.x;
    const int wv = t >> 6, l = t & 63, quad = l >> 4, c = l & 15;

    // ---- scalars + ee W2 frags from global ----
    f16x8 b2f[2];
    #pragma unroll
    for (int Kt = 0; Kt < 2; ++Kt) {
        union { uint32_t d[4]; f16x8 v; } f;
        #pragma unroll
        for (int d2 = 0; d2 < 4; ++d2) {
            int k0 = Kt * 32 + quad * 8 + 2 * d2;
            union { _Float16 h[2]; uint32_t u; } pk;
            pk.h[0] = (_Float16)((k0 < E1 && c < E2) ? ew2[k0 * E2 + c] : 0.f);
            pk.h[1] = (_Float16)((k0 + 1 < E1 && c < E2) ? ew2[(k0 + 1) * E2 + c] : 0.f);
            f.d[d2] = pk.u;
        }
        b2f[Kt] = f.v;
    }
    float eb1v[3];
    #pragma unroll
    for (int Nt = 0; Nt < 3; ++Nt) { int n = Nt * 16 + c; eb1v[Nt] = (n < E1) ? eb1[n] : 0.f; }
    const float eb2v = (c < E2) ? eb2[c] : 0.f;
    const float w3v  = (c < E2) ? ew3[c] : 0.f;
    const float eb3v = eb3[0];

    // ---- stage xs[b] fp32 -> fp16 LDS ----
    {
        const float4* src = (const float4*)(xs + (size_t)b * N_ * D_);
        #pragma unroll
        for (int u = 0; u < 4; ++u) {
            int q = t + 512 * u;              // 2048 float4
            float4 v = src[q];
            int row = q >> 6, col4 = q & 63;
            union { _Float16 h[4]; uint64_t u64; } pk;
            pk.h[0] = (_Float16)v.x; pk.h[1] = (_Float16)v.y;
            pk.h[2] = (_Float16)v.z; pk.h[3] = (_Float16)v.w;
            *(uint64_t*)&xs_h[row * XBP + col4 * 4] = pk.u64;
        }
    }
    // ---- stage ew1 [256][40] -> ew1T [40 n][264 k] f16 (transposed) ----
    {
        const float4* src = (const float4*)ew1;   // 2560 float4
        #pragma unroll
        for (int u = 0; u < 5; ++u) {
            int q = t + 512 * u;
            float4 v = src[q];
            int k = q / 10, n0 = (q - 10 * k) * 4;
            wbuf[(n0 + 0) * EWT + k] = (_Float16)v.x;
            wbuf[(n0 + 1) * EWT + k] = (_Float16)v.y;
            wbuf[(n0 + 2) * EWT + k] = (_Float16)v.z;
            wbuf[(n0 + 3) * EWT + k] = (_Float16)v.w;
        }
    }
    // zero h1e cols 80..95 (layer-2 K-pad; col 80 rewritten by wave 5)
    if (t < 128) {
        int m = t >> 2, q4 = t & 3;
        *(uint64_t*)(uni + 9216 + m * (HEP * 2) + 160 + q4 * 8) = 0ull;
    }
    if (t < N_ * 3) rs_s[t] = rs[b * N_ * 3 + t];
    if (t < N2 * N3) nw3_s[t] = nw3[t];
    if (t < N2) nb2_s[t] = nb2[t];
    if (t < N3) nb3_s[t] = nb3[t];
    if (t < K_ * 3) co_s[t] = coords[t];
    __syncthreads();   // B1: xs_h + ew1T + h1e-pad + misc ready

    // ---- en layer 1: wave wv<6 owns Nt=wv (both Mt), private tile, NO barriers
    if (wv < 6) {
        _Float16* tile = (_Float16*)uni + wv * TILE16;   // [16 n][TKP k]
        const int ln = l & 15, lq = l >> 4;
        const int gn = wv * 16 + ln;                     // staged col (n)
        const bool gok = (gn < N1);
        const int n_col = wv * 16 + c;                   // MFMA col (n)
        const float nb1v = (n_col < N1) ? nb1[n_col] : 0.f;

        float pf[8];
        #pragma unroll
        for (int u = 0; u < 8; ++u)
            pf[u] = gok ? nw1[(lq + 4 * u) * N1 + gn] : 0.f;

        f32x4 acc[2];
        acc[0] = (f32x4){0.f, 0.f, 0.f, 0.f};
        acc[1] = (f32x4){0.f, 0.f, 0.f, 0.f};

        #pragma unroll 1
        for (int Kt = 0; Kt < 8; ++Kt) {
            #pragma unroll
            for (int u = 0; u < 8; ++u)
                tile[ln * TKP + lq + 4 * u] = (_Float16)pf[u];
            if (Kt < 7) {
                const float* wk = nw1 + (Kt + 1) * 32 * N1 + gn;
                #pragma unroll
                for (int u = 0; u < 8; ++u)
                    pf[u] = gok ? wk[(lq + 4 * u) * N1] : 0.f;
            }
            // same-wave RAW: compiler inserts lgkmcnt before this read
            f16x8 Bf = *(const f16x8*)&tile[c * TKP + quad * 8];
            #pragma unroll
            for (int Mt = 0; Mt < 2; ++Mt) {
                f16x8 A = *(const f16x8*)&xs_h[(Mt * 16 + c) * XBP + Kt * 32 + quad * 8];
                acc[Mt] = __builtin_amdgcn_mfma_f32_16x16x32_f16(A, Bf, acc[Mt], 0, 0, 0);
            }
        }
        if (n_col < N1) {
            #pragma unroll
            for (int Mt = 0; Mt < 2; ++Mt)
                #pragma unroll
                for (int r2 = 0; r2 < 4; ++r2) {
                    int m = Mt * 16 + quad * 4 + r2;
                    h1e[m * HEP + n_col] = (_Float16)sspf(acc[Mt][r2] + nb1v);
                }
        }
    }
    __syncthreads();   // B3: h1e done, tiles dead, ew1T still intact

    // ---- build ee W1 fragments from ew1T (VGPR-resident from here on) ----
    f16x8 b1f[3][8];
    #pragma unroll
    for (int Nt = 0; Nt < 3; ++Nt) {
        int n = Nt * 16 + c;
        bool ok = (n < E1);
        int row = ok ? n : 0;
        #pragma unroll
        for (int Kt = 0; Kt < 8; ++Kt) {
            f16x8 v = *(const f16x8*)&wbuf[row * EWT + Kt * 32 + quad * 8];
            if (!ok) v = (f16x8)(_Float16)0.f;
            b1f[Nt][Kt] = v;
        }
    }
    // ---- stage nw2T [32 n][NWP k] f16 into dead tile region ----
    #pragma unroll
    for (int u = 0; u < 6; ++u) {
        int idx = t + 512 * u;                // 3072 = 32 n x 96 kk
        int n = idx / 96, kk = idx - 96 * n;
        float v = (kk < N1 && n < N2) ? nw2[kk * N2 + n] : 0.f;
        nw2T[n * NWP + kk] = (_Float16)v;
    }
    __syncthreads();   // B5: nw2T ready (b1f reads of wbuf also done)

    // ---- en layer 2 via MFMA (waves 0..3): h2 = ssp(h1e @ nw2 + nb2) ----
    if (wv < 4) {
        const int Mt = wv & 1, Nt = wv >> 1;
        f32x4 acc2 = {0.f, 0.f, 0.f, 0.f};
        #pragma unroll
        for (int Kt2 = 0; Kt2 < 3; ++Kt2) {
            f16x8 A  = *(const f16x8*)&h1e[(Mt * 16 + c) * HEP + Kt2 * 32 + quad * 8];
            f16x8 Bf = *(const f16x8*)&nw2T[(Nt * 16 + c) * NWP + Kt2 * 32 + quad * 8];
            acc2 = __builtin_amdgcn_mfma_f32_16x16x32_f16(A, Bf, acc2, 0, 0, 0);
        }
        int n = Nt * 16 + c;
        if (n < N2) {
            #pragma unroll
            for (int r2 = 0; r2 < 4; ++r2) {
                int m = Mt * 16 + quad * 4 + r2;
                h2e[m * 26 + n] = sspf(acc2[r2] + nb2_s[n]);
            }
        }
    }
    __syncthreads();   // B6: h2e complete

    // ---- en layer 3 + bf_nuc + cutoff (threads 0..255: 32 rows x 8 nuclei) ----
    if (t < 256) {
        const int r = t >> 3, s = t & 7;
        float w = nb3_s[s];
        const int rb = r * 26;
        #pragma unroll
        for (int kk = 0; kk < N2; ++kk)
            w = fmaf(h2e[rb + kk], nw3_s[kk * N3 + s], w);

        float dx = rs_s[r * 3 + 0] - co_s[s * 3 + 0];
        float dy = rs_s[r * 3 + 1] - co_s[s * 3 + 1];
        float dz = rs_s[r * 3 + 2] - co_s[s * 3 + 2];
        float cx = w * dx, cy = w * dy, cz = w * dz;
        #pragma unroll
        for (int m2 = 1; m2 < 8; m2 <<= 1) {
            cx += __shfl_xor(cx, m2);
            cy += __shfl_xor(cy, m2);
            cz += __shfl_xor(cz, m2);
        }
        float rr  = sqrtf(dx * dx + dy * dy + dz * dz);
        float xsc = 2.f * rr;                 // r / L, L = 0.5
        float cf  = (xsc < 0.5f) ? xsc * xsc * (6.f - 8.f * xsc + 3.f * xsc * xsc) : 1.f;
        #pragma unroll
        for (int m2 = 1; m2 < 8; m2 <<= 1) cf *= __shfl_xor(cf, m2);
        if (s == 0) {
            bfn_s[r * 3 + 0] = cx;
            bfn_s[r * 3 + 1] = cy;
            bfn_s[r * 3 + 2] = cz;
            cut_s[r] = cf;
        }
    }
    __syncthreads();   // B7: en done; uni free for h1t

    // zero h1t cols 48..63 (A-operand pad for ee layer-2 MFMA must be finite)
    _Float16* myh1 = (_Float16*)(uni + wv * (16 * H1P * 2));
    *(uint64_t*)&myh1[c * H1P + 48 + quad * 4] = 0ull;

    // ---- ee main: 4 i per wave; h=0/1 -> j=0..15 / 16..31 ----
    #pragma unroll 1
    for (int q8 = 0; q8 < 4; ++q8) {
        const int i = wv + 8 * q8;
        f32x4 acc[2][3];
        #pragma unroll
        for (int h = 0; h < 2; ++h)
            #pragma unroll
            for (int Nt = 0; Nt < 3; ++Nt) acc[h][Nt] = (f32x4){0.f, 0.f, 0.f, 0.f};

        #pragma unroll
        for (int Kt = 0; Kt < 8; ++Kt) {
            const int koff = Kt * 32 + quad * 8;
            f16x8 iv  = *(const f16x8*)&xs_h[i * XBP + koff];
            f16x8 jv0 = *(const f16x8*)&xs_h[c * XBP + koff];
            f16x8 jv1 = *(const f16x8*)&xs_h[(16 + c) * XBP + koff];
            f16x8 A0 = iv * jv0;               // v_pk_mul_f16 x4
            f16x8 A1 = iv * jv1;
            #pragma unroll
            for (int Nt = 0; Nt < 3; ++Nt) {
                acc[0][Nt] = __builtin_amdgcn_mfma_f32_16x16x32_f16(A0, b1f[Nt][Kt], acc[0][Nt], 0, 0, 0);
                acc[1][Nt] = __builtin_amdgcn_mfma_f32_16x16x32_f16(A1, b1f[Nt][Kt], acc[1][Nt], 0, 0, 0);
            }
        }

        // epilogue: h1 -> LDS swap -> layer2 MFMA -> layer3 -> inline contraction
        const float rix = rs_s[i * 3 + 0], riy = rs_s[i * 3 + 1], riz = rs_s[i * 3 + 2];
        float cxi = 0.f, cyi = 0.f, czi = 0.f;
        #pragma unroll
        for (int h = 0; h < 2; ++h) {
            #pragma unroll
            for (int Nt = 0; Nt < 3; ++Nt) {
                #pragma unroll
                for (int r2 = 0; r2 < 4; ++r2) {
                    float hv = sspf(acc[h][Nt][r2] + eb1v[Nt]);
                    myh1[(quad * 4 + r2) * H1P + Nt * 16 + c] = (_Float16)hv;
                }
            }
            f32x4 acc2 = {0.f, 0.f, 0.f, 0.f};
            #pragma unroll
            for (int Kt2 = 0; Kt2 < 2; ++Kt2) {
                f16x8 a2 = *(const f16x8*)&myh1[c * H1P + Kt2 * 32 + quad * 8];
                acc2 = __builtin_amdgcn_mfma_f32_16x16x32_f16(a2, b2f[Kt2], acc2, 0, 0, 0);
            }
            float wp[4];
            #pragma unroll
            for (int r2 = 0; r2 < 4; ++r2) wp[r2] = sspf(acc2[r2] + eb2v) * w3v;
            #pragma unroll
            for (int m2 = 1; m2 < 16; m2 <<= 1) {   // allreduce over c
                #pragma unroll
                for (int r2 = 0; r2 < 4; ++r2) wp[r2] += __shfl_xor(wp[r2], m2);
            }
            #pragma unroll
            for (int r2 = 0; r2 < 4; ++r2) {
                int j = quad * 4 + r2 + 16 * h;
                float wj = wp[r2] + eb3v;
                cxi = fmaf(wj, rix - rs_s[j * 3 + 0], cxi);
                cyi = fmaf(wj, riy - rs_s[j * 3 + 1], cyi);
                czi = fmaf(wj, riz - rs_s[j * 3 + 2], czi);
            }
        }
        #pragma unroll
        for (int m2 = 16; m2 < 64; m2 <<= 1) {
            cxi += __shfl_xor(cxi, m2);
            cyi += __shfl_xor(cyi, m2);
            czi += __shfl_xor(czi, m2);
        }
        if (l == 0) {
            bfe_s[i * 3 + 0] = cxi;
            bfe_s[i * 3 + 1] = cyi;
            bfe_s[i * 3 + 2] = czi;
        }
    }
    __syncthreads();   // B8: bfe_s ready

    // ---- final combine + store (threads 0..95) ----
    if (t < N_ * 3) {
        int i = t / 3;
        out[(size_t)b * (N_ * 3) + t] =
            rs_s[t] + 1e-4f * cut_s[i] * (bfe_s[t] + bfn_s[t]);
    }
}

extern "C" void kernel_launch(void* const* d_in, const int* in_sizes, int n_in,
                              void* d_out, int out_size, void* d_ws, size_t ws_size,
                              hipStream_t stream)
{
    const float* rs     = (const float*)d_in[0];
    const float* xs     = (const float*)d_in[1];
    const float* coords = (const float*)d_in[2];
    const float* ew1    = (const float*)d_in[3];
    const float* eb1    = (const float*)d_in[4];
    const float* ew2    = (const float*)d_in[5];
    const float* eb2    = (const float*)d_in[6];
    const float* ew3    = (const float*)d_in[7];
    const float* eb3    = (const float*)d_in[8];
    const float* nw1    = (const float*)d_in[9];
    const float* nb1    = (const float*)d_in[10];
    const float* nw2    = (const float*)d_in[11];
    const float* nb2    = (const float*)d_in[12];
    const float* nw3    = (const float*)d_in[13];
    const float* nb3    = (const float*)d_in[14];

    k_fused<<<B_, 512, 0, stream>>>(rs, xs, coords, ew1, eb1, ew2, eb2, ew3, eb3,
                                    nw1, nb1, nw2, nb2, nw3, nb3, (float*)d_out);
}

// Round 13
// 127.585 us; speedup vs baseline: 1.5178x; 1.0491x over previous
//
#include <hip/hip_runtime.h>
#include <stdint.h>

static constexpr int B_ = 512, N_ = 32, D_ = 256, K_ = 8;
static constexpr int E1 = 40, E2 = 6;          // ee MLP dims 256->40->6->1
static constexpr int N1 = 81, N2 = 25, N3 = 8; // en MLP dims 256->81->25->8
static constexpr int XBP = 264;                // xs_h row stride (f16), 528 B, 16B-aligned
static constexpr int HEP = 96;                 // h1e row stride (f16), 192 B, 16B-aligned
static constexpr int EWT = 264;                // ew1T row stride (f16), 528 B
static constexpr int TKP = 48;                 // en tile k-stride (f16), 96 B, 16B-aligned
static constexpr int NWP = 104;                // nw2T row stride (f16), 208 B, 16B-aligned
static constexpr int TILE16 = 16 * TKP;       // per-wave en tile, f16 elems (1536 B)
static constexpr float LN2f  = 0.69314718055994530942f;
static constexpr float L2Ef  = 1.44269504088896340736f;

typedef float    f32x4 __attribute__((ext_vector_type(4)));
typedef _Float16 f16x8 __attribute__((ext_vector_type(8)));
typedef _Float16 f16x4 __attribute__((ext_vector_type(4)));

#if __has_builtin(__builtin_amdgcn_mfma_f32_16x16x16_f16)
#define MFMA16(A, B, C) __builtin_amdgcn_mfma_f32_16x16x16_f16((A), (B), (C), 0, 0, 0)
#else
#define MFMA16(A, B, C) __builtin_amdgcn_mfma_f32_16x16x16f16((A), (B), (C), 0, 0, 0)
#endif

// base-2 shifted softplus: returns ssp(x)/ln2 where t = x*log2e.
// Weights/biases are pre-scaled so inputs arrive as t and the ln2 output
// scale is folded into the next layer's weights (ln2*log2e = 1 keeps W2 raw).
__device__ __forceinline__ float ssp2(float t) {
    float e = __builtin_amdgcn_exp2f(t);
    return __builtin_amdgcn_logf(fmaf(e, 0.5f, 0.5f));   // v_log_f32 = log2
}

// single fused kernel; grid = B_ (one block per batch), 512 threads (8 waves)
// NOTE: no occupancy arg in launch_bounds (R10: pinning forced VGPR<=64 and
// spilled b1f; allocator floats to 128 = 2 blocks/CU).
__global__ __launch_bounds__(512) void k_fused(
    const float* __restrict__ rs, const float* __restrict__ xs,
    const float* __restrict__ coords,
    const float* __restrict__ ew1, const float* __restrict__ eb1,
    const float* __restrict__ ew2, const float* __restrict__ eb2,
    const float* __restrict__ ew3, const float* __restrict__ eb3,
    const float* __restrict__ nw1, const float* __restrict__ nb1,
    const float* __restrict__ nw2, const float* __restrict__ nb2,
    const float* __restrict__ nw3, const float* __restrict__ nb3,
    float* __restrict__ out)
{
    __shared__ alignas(16) _Float16 xs_h[N_ * XBP];    // 16896 B
    __shared__ alignas(16) _Float16 wbuf[E1 * EWT];    // 21120 B: ew1T (*log2e)
    // uni, en phase only now:
    //   [0,9216) 6 per-wave nw1 tiles -> then nw2T (6656 B)
    //   [9216,15360) h1e f16 [32][96]; [15360,18688) h2e f32 [32][26]
    __shared__ alignas(16) char uni[18688];
    __shared__ float nw3_s[N2 * N3];
    __shared__ float rs_s[N_ * 3];
    __shared__ float nb2_s[N2];
    __shared__ float nb3_s[N3];
    __shared__ float co_s[K_ * 3];
    __shared__ float bfn_s[N_ * 3];
    __shared__ float cut_s[N_];
    __shared__ float bfe_s[N_ * 3];
    __shared__ alignas(16) float eb1_s[48];            // eb1*log2e, padded
    __shared__ alignas(16) float b2_s[16];             // eb2*log2e, padded

    _Float16* h1e  = (_Float16*)(uni + 9216);          // [32][HEP]
    float*    h2e  = (float*)(uni + 15360);            // [32][26]
    _Float16* nw2T = (_Float16*)uni;                   // [32][NWP] (en L2 phase)

    const int b = blockIdx.x, t = threadIdx.x;
    const int wv = t >> 6, l = t & 63, quad = l >> 4, c = l & 15;

    // ---- static per-lane constants ----
    // ee W2^T as MFMA16 A-frags: A[m=c][k=quad*4+r] per Nt = W2[n=16Nt+quad*4+r][m=c]
    f16x4 b2fT[3];
    #pragma unroll
    for (int Nt = 0; Nt < 3; ++Nt) {
        f16x4 p;
        #pragma unroll
        for (int r = 0; r < 4; ++r) {
            int n = Nt * 16 + quad * 4 + r;
            p[r] = (_Float16)((n < E1 && c < E2) ? ew2[n * E2 + c] : 0.f);
        }
        b2fT[Nt] = p;
    }
    float w3q[4];   // w3*ln2 by row m=quad*4+r
    #pragma unroll
    for (int r = 0; r < 4; ++r) {
        int m = quad * 4 + r;
        w3q[r] = (m < E2) ? ew3[m] * LN2f : 0.f;
    }
    const float eb3v = eb3[0];

    // ---- stage xs[b] fp32 -> fp16 LDS ----
    {
        const float4* src = (const float4*)(xs + (size_t)b * N_ * D_);
        #pragma unroll
        for (int u = 0; u < 4; ++u) {
            int q = t + 512 * u;              // 2048 float4
            float4 v = src[q];
            int row = q >> 6, col4 = q & 63;
            union { _Float16 h[4]; uint64_t u64; } pk;
            pk.h[0] = (_Float16)v.x; pk.h[1] = (_Float16)v.y;
            pk.h[2] = (_Float16)v.z; pk.h[3] = (_Float16)v.w;
            *(uint64_t*)&xs_h[row * XBP + col4 * 4] = pk.u64;
        }
    }
    // ---- stage ew1*log2e [256][40] -> ew1T [40 n][264 k] f16 (transposed) ----
    {
        const float4* src = (const float4*)ew1;   // 2560 float4
        #pragma unroll
        for (int u = 0; u < 5; ++u) {
            int q = t + 512 * u;
            float4 v = src[q];
            int k = q / 10, n0 = (q - 10 * k) * 4;
            wbuf[(n0 + 0) * EWT + k] = (_Float16)(v.x * L2Ef);
            wbuf[(n0 + 1) * EWT + k] = (_Float16)(v.y * L2Ef);
            wbuf[(n0 + 2) * EWT + k] = (_Float16)(v.z * L2Ef);
            wbuf[(n0 + 3) * EWT + k] = (_Float16)(v.w * L2Ef);
        }
    }
    // zero h1e cols 80..95 (layer-2 K-pad; col 80 rewritten by wave 5)
    if (t < 128) {
        int m = t >> 2, q4 = t & 3;
        *(uint64_t*)(uni + 9216 + m * (HEP * 2) + 160 + q4 * 8) = 0ull;
    }
    if (t < N_ * 3) rs_s[t] = rs[b * N_ * 3 + t];
    if (t < N2 * N3) nw3_s[t] = nw3[t] * LN2f;
    if (t < N2) nb2_s[t] = nb2[t] * L2Ef;
    if (t < N3) nb3_s[t] = nb3[t];
    if (t < K_ * 3) co_s[t] = coords[t];
    if (t < 48) eb1_s[t] = (t < E1) ? eb1[t] * L2Ef : 0.f;
    if (t < 16) b2_s[t] = (t < E2) ? eb2[t] * L2Ef : 0.f;
    __syncthreads();   // B1: xs_h + ew1T + h1e-pad + misc ready

    // ---- en layer 1: wave wv<6 owns Nt=wv (both Mt), private tile, NO barriers
    if (wv < 6) {
        _Float16* tile = (_Float16*)uni + wv * TILE16;   // [16 n][TKP k]
        const int ln = l & 15, lq = l >> 4;
        const int gn = wv * 16 + ln;                     // staged col (n)
        const bool gok = (gn < N1);
        const int n_col = wv * 16 + c;                   // MFMA col (n)
        const float nb1v = (n_col < N1) ? nb1[n_col] * L2Ef : 0.f;

        float pf[8];
        #pragma unroll
        for (int u = 0; u < 8; ++u)
            pf[u] = gok ? nw1[(lq + 4 * u) * N1 + gn] : 0.f;

        f32x4 acc[2];
        acc[0] = (f32x4){0.f, 0.f, 0.f, 0.f};
        acc[1] = (f32x4){0.f, 0.f, 0.f, 0.f};

        #pragma unroll 1
        for (int Kt = 0; Kt < 8; ++Kt) {
            #pragma unroll
            for (int u = 0; u < 8; ++u)
                tile[ln * TKP + lq + 4 * u] = (_Float16)(pf[u] * L2Ef);
            if (Kt < 7) {
                const float* wk = nw1 + (Kt + 1) * 32 * N1 + gn;
                #pragma unroll
                for (int u = 0; u < 8; ++u)
                    pf[u] = gok ? wk[(lq + 4 * u) * N1] : 0.f;
            }
            // same-wave RAW: compiler inserts lgkmcnt before this read
            f16x8 Bf = *(const f16x8*)&tile[c * TKP + quad * 8];
            #pragma unroll
            for (int Mt = 0; Mt < 2; ++Mt) {
                f16x8 A = *(const f16x8*)&xs_h[(Mt * 16 + c) * XBP + Kt * 32 + quad * 8];
                acc[Mt] = __builtin_amdgcn_mfma_f32_16x16x32_f16(A, Bf, acc[Mt], 0, 0, 0);
            }
        }
        if (n_col < N1) {
            #pragma unroll
            for (int Mt = 0; Mt < 2; ++Mt)
                #pragma unroll
                for (int r2 = 0; r2 < 4; ++r2) {
                    int m = Mt * 16 + quad * 4 + r2;
                    h1e[m * HEP + n_col] = (_Float16)ssp2(acc[Mt][r2] + nb1v);
                }
        }
    }
    __syncthreads();   // B3: h1e done, tiles dead, ew1T still intact

    // ---- build ee W1^T A-frags from ew1T (24 ds_read_b128 per lane) ----
    // A-layout: lane(quad,c) holds A[n=c+16Nt][k=quad*8+d+32Kt] — same LDS read
    // pattern as the old B-frag build; only the MFMA role changes.
    f16x8 b1f[3][8];
    #pragma unroll
    for (int Nt = 0; Nt < 3; ++Nt) {
        int n = Nt * 16 + c;
        bool ok = (n < E1);
        int row = ok ? n : 0;
        #pragma unroll
        for (int Kt = 0; Kt < 8; ++Kt) {
            f16x8 v = *(const f16x8*)&wbuf[row * EWT + Kt * 32 + quad * 8];
            if (!ok) v = (f16x8)(_Float16)0.f;
            b1f[Nt][Kt] = v;
        }
    }
    // ---- stage nw2T [32 n][NWP k] f16 into dead tile region ----
    #pragma unroll
    for (int u = 0; u < 6; ++u) {
        int idx = t + 512 * u;                // 3072 = 32 n x 96 kk
        int n = idx / 96, kk = idx - 96 * n;
        float v = (kk < N1 && n < N2) ? nw2[kk * N2 + n] : 0.f;
        nw2T[n * NWP + kk] = (_Float16)v;
    }
    __syncthreads();   // B5: nw2T ready (b1f reads of wbuf also done)

    // ---- en layer 2 via MFMA (waves 0..3): h2 = ssp2(h1e @ nw2 + nb2') ----
    if (wv < 4) {
        const int Mt = wv & 1, Nt = wv >> 1;
        f32x4 acc2 = {0.f, 0.f, 0.f, 0.f};
        #pragma unroll
        for (int Kt2 = 0; Kt2 < 3; ++Kt2) {
            f16x8 A  = *(const f16x8*)&h1e[(Mt * 16 + c) * HEP + Kt2 * 32 + quad * 8];
            f16x8 Bf = *(const f16x8*)&nw2T[(Nt * 16 + c) * NWP + Kt2 * 32 + quad * 8];
            acc2 = __builtin_amdgcn_mfma_f32_16x16x32_f16(A, Bf, acc2, 0, 0, 0);
        }
        int n = Nt * 16 + c;
        if (n < N2) {
            #pragma unroll
            for (int r2 = 0; r2 < 4; ++r2) {
                int m = Mt * 16 + quad * 4 + r2;
                h2e[m * 26 + n] = ssp2(acc2[r2] + nb2_s[n]);
            }
        }
    }
    __syncthreads();   // B6: h2e complete

    // ---- en layer 3 + bf_nuc + cutoff (threads 0..255; waves 4-7 fall through
    //      into ee main and overlap this) ----
    if (t < 256) {
        const int r = t >> 3, s = t & 7;
        float w = nb3_s[s];
        const int rb = r * 26;
        #pragma unroll
        for (int kk = 0; kk < N2; ++kk)
            w = fmaf(h2e[rb + kk], nw3_s[kk * N3 + s], w);

        float dx = rs_s[r * 3 + 0] - co_s[s * 3 + 0];
        float dy = rs_s[r * 3 + 1] - co_s[s * 3 + 1];
        float dz = rs_s[r * 3 + 2] - co_s[s * 3 + 2];
        float cx = w * dx, cy = w * dy, cz = w * dz;
        #pragma unroll
        for (int m2 = 1; m2 < 8; m2 <<= 1) {
            cx += __shfl_xor(cx, m2);
            cy += __shfl_xor(cy, m2);
            cz += __shfl_xor(cz, m2);
        }
        float rr  = sqrtf(dx * dx + dy * dy + dz * dz);
        float xsc = 2.f * rr;                 // r / L, L = 0.5
        float cf  = (xsc < 0.5f) ? xsc * xsc * (6.f - 8.f * xsc + 3.f * xsc * xsc) : 1.f;
        #pragma unroll
        for (int m2 = 1; m2 < 8; m2 <<= 1) cf *= __shfl_xor(cf, m2);
        if (s == 0) {
            bfn_s[r * 3 + 0] = cx;
            bfn_s[r * 3 + 1] = cy;
            bfn_s[r * 3 + 2] = cz;
            cut_s[r] = cf;
        }
    }
    // no barrier: bfn_s/cut_s only read after B8 below

    // ---- ee main: 4 i per wave; h=0/1 -> j=0..15 / 16..31 ----
    // Layer-1: D = W1'^T (A) x P (B) -> h1^T C-layout [n=quad*4+r2][j=c],
    // which IS the 16x16x16 B-operand layout -> layer-2 straight from registers.
    #pragma unroll 1
    for (int q8 = 0; q8 < 4; ++q8) {
        const int i = wv + 8 * q8;
        f32x4 acc[2][3];
        #pragma unroll
        for (int Nt = 0; Nt < 3; ++Nt) {
            f32x4 bias = *(const f32x4*)&eb1_s[Nt * 16 + quad * 4];
            acc[0][Nt] = bias;
            acc[1][Nt] = bias;
        }

        #pragma unroll
        for (int Kt = 0; Kt < 8; ++Kt) {
            const int koff = Kt * 32 + quad * 8;
            f16x8 iv  = *(const f16x8*)&xs_h[i * XBP + koff];
            f16x8 jv0 = *(const f16x8*)&xs_h[c * XBP + koff];
            f16x8 jv1 = *(const f16x8*)&xs_h[(16 + c) * XBP + koff];
            f16x8 P0 = iv * jv0;               // B-operand: B[k][j=c]
            f16x8 P1 = iv * jv1;
            #pragma unroll
            for (int Nt = 0; Nt < 3; ++Nt) {
                acc[0][Nt] = __builtin_amdgcn_mfma_f32_16x16x32_f16(b1f[Nt][Kt], P0, acc[0][Nt], 0, 0, 0);
                acc[1][Nt] = __builtin_amdgcn_mfma_f32_16x16x32_f16(b1f[Nt][Kt], P1, acc[1][Nt], 0, 0, 0);
            }
        }

        // epilogue: act -> pack -> MFMA16 x3 -> act -> 2-shfl allred -> contract
        const float rix = rs_s[i * 3 + 0], riy = rs_s[i * 3 + 1], riz = rs_s[i * 3 + 2];
        float cxi = 0.f, cyi = 0.f, czi = 0.f;
        const f32x4 b2i = *(const f32x4*)&b2_s[quad * 4];
        #pragma unroll
        for (int h = 0; h < 2; ++h) {
            f32x4 acc2 = b2i;
            #pragma unroll
            for (int Nt = 0; Nt < 3; ++Nt) {
                f16x4 bh;
                #pragma unroll
                for (int r2 = 0; r2 < 4; ++r2)
                    bh[r2] = (_Float16)ssp2(acc[h][Nt][r2]);   // bias pre-folded
                acc2 = MFMA16(b2fT[Nt], bh, acc2);
            }
            float ws = 0.f;
            #pragma unroll
            for (int r2 = 0; r2 < 4; ++r2)
                ws = fmaf(w3q[r2], ssp2(acc2[r2]), ws);
            ws += __shfl_xor(ws, 16);
            ws += __shfl_xor(ws, 32);          // allreduce over m (quads)
            float wj = ws + eb3v;
            int j = c + 16 * h;
            cxi = fmaf(wj, rix - rs_s[j * 3 + 0], cxi);
            cyi = fmaf(wj, riy - rs_s[j * 3 + 1], cyi);
            czi = fmaf(wj, riz - rs_s[j * 3 + 2], czi);
        }
        // reduce over j (c lanes); quads hold identical replicas
        #pragma unroll
        for (int m2 = 1; m2 < 16; m2 <<= 1) {
            cxi += __shfl_xor(cxi, m2);
            cyi += __shfl_xor(cyi, m2);
            czi += __shfl_xor(czi, m2);
        }
        if (l == 0) {
            bfe_s[i * 3 + 0] = cxi;
            bfe_s[i * 3 + 1] = cyi;
            bfe_s[i * 3 + 2] = czi;
        }
    }
    __syncthreads();   // B8: bfe_s (+ bfn_s/cut_s) ready

    // ---- final combine + store (threads 0..95) ----
    if (t < N_ * 3) {
        int i = t / 3;
        out[(size_t)b * (N_ * 3) + t] =
            rs_s[t] + 1e-4f * cut_s[i] * (bfe_s[t] + bfn_s[t]);
    }
}

extern "C" void kernel_launch(void* const* d_in, const int* in_sizes, int n_in,
                              void* d_out, int out_size, void* d_ws, size_t ws_size,
                              hipStream_t stream)
{
    const float* rs     = (const float*)d_in[0];
    const float* xs     = (const float*)d_in[1];
    const float* coords = (const float*)d_in[2];
    const float* ew1    = (const float*)d_in[3];
    const float* eb1    = (const float*)d_in[4];
    const float* ew2    = (const float*)d_in[5];
    const float* eb2    = (const float*)d_in[6];
    const float* ew3    = (const float*)d_in[7];
    const float* eb3    = (const float*)d_in[8];
    const float* nw1    = (const float*)d_in[9];
    const float* nb1    = (const float*)d_in[10];
    const float* nw2    = (const float*)d_in[11];
    const float* nb2    = (const float*)d_in[12];
    const float* nw3    = (const float*)d_in[13];
    const float* nb3    = (const float*)d_in[14];

    k_fused<<<B_, 512, 0, stream>>>(rs, xs, coords, ew1, eb1, ew2, eb2, ew3, eb3,
                                    nw1, nb1, nw2, nb2, nw3, nb3, (float*)d_out);
}